// Round 14
// baseline (397.354 us; speedup 1.0000x reference)
//
#include <hip/hip_runtime.h>

#define CH 128

typedef _Float16 f16;
typedef _Float16 f16x8 __attribute__((ext_vector_type(8)));
typedef float f32x4 __attribute__((ext_vector_type(4)));

__device__ __forceinline__ f32x4 mfma16(f16x8 a, f16x8 b, f32x4 c) {
    return __builtin_amdgcn_mfma_f32_16x16x32_f16(a, b, c, 0, 0, 0);
}

// ---------------- fused front: hist(+rank) + weight prep (3 layers) ----------------
__global__ __launch_bounds__(256) void k_front(const int* __restrict__ edst, int* __restrict__ counts,
                                               int* __restrict__ erank, int E,
                                               const float* __restrict__ W1a, const float* __restrict__ W2a,
                                               const float* __restrict__ W1b, const float* __restrict__ W2b,
                                               const float* __restrict__ W1c, const float* __restrict__ W2c,
                                               f16* __restrict__ WcT, f16* __restrict__ W2T,
                                               int gHist) {
    int bid = blockIdx.x;
    if (bid < gHist) {
        int e = bid * 256 + threadIdx.x;
        if (e < E) erank[e] = atomicAdd(&counts[edst[e]], 1);   // rank doubles as scatter cursor
    } else {
        int r = bid - gHist;
        int l = r / 192;
        const float* W1 = (l == 0) ? W1a : (l == 1) ? W1b : W1c;
        const float* W2 = (l == 0) ? W2a : (l == 1) ? W2b : W2c;
        f16* wct = WcT + l * 256 * CH;
        f16* w2t = W2T + l * CH * CH;
        int id = (r % 192) * 256 + threadIdx.x;   // 49152 per layer
        if (id < 32768) {
            int n = id >> 7, k = id & 127;
            float v;
            if (n < CH) v = W1[k * CH + n] - W1[(CH + k) * CH + n];
            else        v = W1[(CH + k) * CH + (n - CH)];
            wct[n * CH + k] = (f16)v;
        } else {
            int rr = id - 32768;
            int n = rr >> 7, k = rr & 127;
            w2t[n * CH + k] = (f16)W2[k * CH + n];
        }
    }
}

// ---------------- CSR scans + scatter (proven structure) ----------------
__global__ __launch_bounds__(256) void k_scan1(const int* __restrict__ counts, int* __restrict__ row_ptr,
                                               int* __restrict__ blockSums, int n) {
    __shared__ int s[256];
    int t = threadIdx.x;
    int i = blockIdx.x * 256 + t;
    s[t] = (i < n) ? counts[i] : 0;
    __syncthreads();
    for (int off = 1; off < 256; off <<= 1) {
        int x = (t >= off) ? s[t - off] : 0;
        __syncthreads();
        s[t] += x;
        __syncthreads();
    }
    if (i < n) row_ptr[i + 1] = s[t];
    if (t == 255) blockSums[blockIdx.x] = s[255];
}

__global__ __launch_bounds__(256) void k_scan2(const int* __restrict__ blockSums, int* __restrict__ blockOff, int nb) {
    __shared__ int s[256];
    int t = threadIdx.x;
    s[t] = (t < nb) ? blockSums[t] : 0;
    __syncthreads();
    for (int off = 1; off < 256; off <<= 1) {
        int x = (t >= off) ? s[t - off] : 0;
        __syncthreads();
        s[t] += x;
        __syncthreads();
    }
    blockOff[t] = (t == 0) ? 0 : s[t - 1];
}

__global__ __launch_bounds__(256) void k_scan3(int* __restrict__ row_ptr, const int* __restrict__ blockOff, int n) {
    int i = blockIdx.x * 256 + threadIdx.x;
    if (i < n) row_ptr[i + 1] += blockOff[blockIdx.x];
    if (blockIdx.x == 0 && threadIdx.x == 0) row_ptr[0] = 0;
}

// atomic-free scatter: pos = row_ptr[dst] + precomputed rank
__global__ __launch_bounds__(256) void k_scatter(const int* __restrict__ src, const int* __restrict__ dst,
                                                 const int* __restrict__ row_ptr, const int* __restrict__ erank,
                                                 int* __restrict__ sed, int E) {
    int e = blockIdx.x * 256 + threadIdx.x;
    if (e < E) {
        int pos = row_ptr[dst[e]] + erank[e];
        sed[pos] = src[e];
    }
}

// ---------------- node GEMMs: nb-split 4-way for occupancy ----------------
// v2: 196 blocks was <1 block/CU = 1 wave/SIMD, latency-exposed. Block = 256 rows x
// 4 nb-blocks (bid = rowBlock*4 + split) -> 784 blocks = ~3 blocks/CU = 3 waves/SIMD.
// Keeps the 4-row-tile B-amortization (16 B loads feed 64 MFMAs). A rows re-read x4
// (L3-resident, cheap).
__global__ __launch_bounds__(256) void k_gemm1x(const float* __restrict__ xf, const f16* __restrict__ WcT,
                                                const float* __restrict__ b1,
                                                f16* __restrict__ P, f16* __restrict__ Q, int nrows) {
    int t = threadIdx.x;
    int w = t >> 6, lane = t & 63;
    int m = lane & 15, q = lane >> 4;
    int rowbase = (blockIdx.x >> 2) * 256 + w * 64;
    int nblo = (blockIdx.x & 3) * 4;
    f16x8 a[4][4];   // [row-tile][kk]
#pragma unroll
    for (int rt = 0; rt < 4; ++rt) {
        int rowc = min(rowbase + rt * 16 + m, nrows - 1);
        const float* xr = xf + (size_t)rowc * CH;
#pragma unroll
        for (int kk = 0; kk < 4; ++kk) {
            float4 v0 = *(const float4*)(xr + kk * 32 + q * 8);
            float4 v1 = *(const float4*)(xr + kk * 32 + q * 8 + 4);
            f16x8 h;
            h[0] = (f16)v0.x; h[1] = (f16)v0.y; h[2] = (f16)v0.z; h[3] = (f16)v0.w;
            h[4] = (f16)v1.x; h[5] = (f16)v1.y; h[6] = (f16)v1.z; h[7] = (f16)v1.w;
            a[rt][kk] = h;
        }
    }
#pragma unroll
    for (int j = 0; j < 4; ++j) {
        int nb = nblo + j;
        f16x8 b[4];
#pragma unroll
        for (int kk = 0; kk < 4; ++kk)
            b[kk] = *(const f16x8*)(WcT + (nb * 16 + m) * CH + kk * 32 + q * 8);
        int col = nb * 16 + m;
        float bias = (nb < 8) ? b1[col] : 0.f;
#pragma unroll
        for (int rt = 0; rt < 4; ++rt) {
            f32x4 acc = {0.f, 0.f, 0.f, 0.f};
#pragma unroll
            for (int kk = 0; kk < 4; ++kk) acc = mfma16(a[rt][kk], b[kk], acc);
#pragma unroll
            for (int r = 0; r < 4; ++r) {
                int ro = rowbase + rt * 16 + q * 4 + r;
                if (ro < nrows) {
                    float v = acc[r] + bias;
                    if (nb < 8) P[(size_t)ro * CH + col] = (f16)v;
                    else        Q[(size_t)ro * CH + (col - CH)] = (f16)v;
                }
            }
        }
    }
}

__global__ __launch_bounds__(256) void k_gemm1(const f16* __restrict__ act, const f16* __restrict__ WcT,
                                               const float* __restrict__ b1,
                                               f16* __restrict__ P, f16* __restrict__ Q, int nrows) {
    int t = threadIdx.x;
    int w = t >> 6, lane = t & 63;
    int m = lane & 15, q = lane >> 4;
    int rowbase = (blockIdx.x >> 2) * 256 + w * 64;
    int nblo = (blockIdx.x & 3) * 4;
    f16x8 a[4][4];   // [row-tile][kk]
#pragma unroll
    for (int rt = 0; rt < 4; ++rt) {
        int rowc = min(rowbase + rt * 16 + m, nrows - 1);
#pragma unroll
        for (int kk = 0; kk < 4; ++kk)
            a[rt][kk] = *(const f16x8*)(act + (size_t)rowc * CH + kk * 32 + q * 8);
    }
#pragma unroll
    for (int j = 0; j < 4; ++j) {
        int nb = nblo + j;
        f16x8 b[4];
#pragma unroll
        for (int kk = 0; kk < 4; ++kk)
            b[kk] = *(const f16x8*)(WcT + (nb * 16 + m) * CH + kk * 32 + q * 8);
        int col = nb * 16 + m;
        float bias = (nb < 8) ? b1[col] : 0.f;
#pragma unroll
        for (int rt = 0; rt < 4; ++rt) {
            f32x4 acc = {0.f, 0.f, 0.f, 0.f};
#pragma unroll
            for (int kk = 0; kk < 4; ++kk) acc = mfma16(a[rt][kk], b[kk], acc);
#pragma unroll
            for (int r = 0; r < 4; ++r) {
                int ro = rowbase + rt * 16 + q * 4 + r;
                if (ro < nrows) {
                    float v = acc[r] + bias;
                    if (nb < 8) P[(size_t)ro * CH + col] = (f16)v;
                    else        Q[(size_t)ro * CH + (col - CH)] = (f16)v;
                }
            }
        }
    }
}

// ---------------- per-node edge GEMM + register max: 1 wave = 1 dst node ----------------
// v8 (round-11 proven: 63.5us, no spill): v3 pipeline + same-node tile2 fusion — when
// deg>16 the two tiles' B-passes fuse; each W2-fragment ds_read feeds 2 MFMAs.
// B LDS passes/node: 1.46 -> 1.03. FROZEN.
// flags: bit0 relu out, bit1 fp32 final out.
__global__ __launch_bounds__(256, 3)
void k_node(const f16* __restrict__ P, const f16* __restrict__ Q,
            const f16* __restrict__ W2Tg, const float* __restrict__ b2,
            const int* __restrict__ row_ptr, const int* __restrict__ sed,
            f16* __restrict__ act_out, float* __restrict__ final_out,
            int n_nodes, int flags, int nwv) {
    // W2^T in fragment order: chunk cid=(nb*4+kk)*64+lane holds the 16B this lane
    // needs for (nb,kk). ds_read_b128 at lane*16 + imm -> lane-contiguous, conflict-free.
    __shared__ __align__(16) f16 w2lds[8 * 4 * 64 * 8];   // 32 KB

    int t = threadIdx.x;
    int w = t >> 6, lane = t & 63;
    int m = lane & 15, q = lane >> 4;

#pragma unroll
    for (int i = t; i < 2048; i += 256) {
        int nb = i >> 8, rem = i & 255, kk = rem >> 6, ln = rem & 63;
        int mm = ln & 15, qq = ln >> 4;
        *(f16x8*)&w2lds[i * 8] = *(const f16x8*)(W2Tg + (size_t)(nb * 16 + mm) * CH + kk * 32 + qq * 8);
    }
    __syncthreads();

    float biasA = b2[lane], biasB = b2[lane + 64];
    const f16x8 z8 = {};
    const f32x4 z4 = {0.f, 0.f, 0.f, 0.f};

    // in-place A-fragment: qs <- relu(pf + qs)  (pf untouched)
    auto mkAf = [&](const f16x8* pf, f16x8* qs) {
#pragma unroll
        for (int kk = 0; kk < 4; ++kk) qs[kk] = __builtin_elementwise_max(pf[kk] + qs[kk], z8);
    };
    // single-tile B pass (af precomputed)
    auto tile1 = [&](const f16x8* af, float* rmax) {
        unsigned wo = 0;
        asm volatile("" : "+v"(wo));              // per-call opacity: no LICM hoist of LDS reads
        const f16* wb = w2lds + wo + (size_t)lane * 8;
#pragma unroll
        for (int nb = 0; nb < 8; ++nb) {
            f32x4 a0 = z4;
#pragma unroll
            for (int kk = 0; kk < 4; ++kk) {
                f16x8 bq = *(const f16x8*)(wb + (nb * 4 + kk) * 512);
                a0 = mfma16(af[kk], bq, a0);
            }
            rmax[nb] = fmaxf(fmaxf(fmaxf(a0[0], a0[1]), fmaxf(a0[2], a0[3])), rmax[nb]);
        }
    };
    // dual-tile B pass: each bq read feeds both tiles (same node -> shared rmax)
    auto tile2 = [&](const f16x8* af0, const f16x8* af1, float* rmax) {
        unsigned wo = 0;
        asm volatile("" : "+v"(wo));
        const f16* wb = w2lds + wo + (size_t)lane * 8;
#pragma unroll
        for (int nb = 0; nb < 8; ++nb) {
            f32x4 a0 = z4, a1 = z4;
#pragma unroll
            for (int kk = 0; kk < 4; ++kk) {
                f16x8 bq = *(const f16x8*)(wb + (nb * 4 + kk) * 512);
                a0 = mfma16(af0[kk], bq, a0);
                a1 = mfma16(af1[kk], bq, a1);
            }
            a0 = __builtin_elementwise_max(a0, a1);
            rmax[nb] = fmaxf(fmaxf(fmaxf(a0[0], a0[1]), fmaxf(a0[2], a0[3])), rmax[nb]);
        }
    };

    int nA = blockIdx.x * 4 + w;
    if (nA >= n_nodes) return;
    int nmax = n_nodes - 1;

    // ---- prologue: fill 4-stage pipeline ----
    int rsA = row_ptr[nA], reA = row_ptr[nA + 1];
    int nB = nA + nwv; int nBc = min(nB, nmax);
    int rsB = row_ptr[nBc], reB = row_ptr[nBc + 1];
    int nC = nB + nwv; int nCc = min(nC, nmax);
    int rsC = row_ptr[nCc], reC = row_ptr[nCc + 1];

    int lA = (reA > rsA) ? reA - 1 : 0;
    int idx0A = sed[min(rsA + m, lA)];
    int idx1A = sed[min(rsA + 16 + m, lA)];
    int lB = (reB > rsB) ? reB - 1 : 0;
    int idx0B = sed[min(rsB + m, lB)];
    int idx1B = sed[min(rsB + 16 + m, lB)];

    f16x8 pfA[4], qs0A[4];
#pragma unroll
    for (int kk = 0; kk < 4; ++kk) {
        pfA[kk]  = *(const f16x8*)(P + (size_t)nA * CH + kk * 32 + q * 8);
        qs0A[kk] = *(const f16x8*)(Q + (size_t)idx0A * CH + kk * 32 + q * 8);
    }

    while (true) {
        // ---- top: batch-issue all future loads (max bytes in flight) ----
        f16x8 qs1A[4] = {};                       // tile-1 rows for current node (idx1A: 2 iters old)
        if (reA - rsA > 16) {
#pragma unroll
            for (int kk = 0; kk < 4; ++kk)
                qs1A[kk] = *(const f16x8*)(Q + (size_t)idx1A * CH + kk * 32 + q * 8);
        }
        f16x8 qs0B[4], pfB[4];                    // next node's tile-0 + P row
#pragma unroll
        for (int kk = 0; kk < 4; ++kk) {
            qs0B[kk] = *(const f16x8*)(Q + (size_t)idx0B * CH + kk * 32 + q * 8);
            pfB[kk]  = *(const f16x8*)(P + (size_t)nBc * CH + kk * 32 + q * 8);
        }
        int lC = (reC > rsC) ? reC - 1 : 0;       // idx for node 2 ahead
        int idx0C = sed[min(rsC + m, lC)];
        int idx1C = sed[min(rsC + 16 + m, lC)];
        int nD = nC + nwv; int nDc = min(nD, nmax);
        int rsD = row_ptr[nDc], reD = row_ptr[nDc + 1];

        // ---- compute node nA ----
        float o0 = 0.f, o1 = 0.f;
        if (reA > rsA) {
            float rmax[8];
#pragma unroll
            for (int nb = 0; nb < 8; ++nb) rmax[nb] = -3.4e38f;
            mkAf(pfA, qs0A);
            if (reA - rsA > 16) {
                mkAf(pfA, qs1A);
                tile2(qs0A, qs1A, rmax);          // fused B pass for tiles 0+1
            } else {
                tile1(qs0A, rmax);
            }
            for (int tb = rsA + 32; tb < reA; tb += 16) {   // deg>32: rare serial tail
                int s2 = sed[min(tb + m, reA - 1)];
                f16x8 qx[4];
#pragma unroll
                for (int kk = 0; kk < 4; ++kk)
                    qx[kk] = *(const f16x8*)(Q + (size_t)s2 * CH + kk * 32 + q * 8);
                mkAf(pfA, qx);
                tile1(qx, rmax);
            }
            // cross-q reduce: lanes l, l^16, l^32, l^48 hold the 4 row-groups of each col
#pragma unroll
            for (int nb = 0; nb < 8; ++nb) {
                float v = rmax[nb];
                v = fmaxf(v, __shfl_xor(v, 16));
                v = fmaxf(v, __shfl_xor(v, 32));
                rmax[nb] = v;
            }
            float vA = (q & 2) ? ((q & 1) ? rmax[3] : rmax[2]) : ((q & 1) ? rmax[1] : rmax[0]);
            float vB = (q & 2) ? ((q & 1) ? rmax[7] : rmax[6]) : ((q & 1) ? rmax[5] : rmax[4]);
            o0 = vA + biasA;
            o1 = vB + biasB;
            if (flags & 1) { o0 = fmaxf(o0, 0.f); o1 = fmaxf(o1, 0.f); }
        }
        if (flags & 2) {
            float* orow = final_out + (size_t)nA * CH;
            orow[lane] = o0; orow[lane + 64] = o1;
        } else {
            f16* orow = act_out + (size_t)nA * CH;
            orow[lane] = (f16)o0; orow[lane + 64] = (f16)o1;
        }

        if (nB >= n_nodes) break;

        // ---- rotate pipeline ----
        nA = nB; rsA = rsB; reA = reB; idx1A = idx1B;
#pragma unroll
        for (int kk = 0; kk < 4; ++kk) { qs0A[kk] = qs0B[kk]; pfA[kk] = pfB[kk]; }
        idx0B = idx0C; idx1B = idx1C;
        nB = nC; nBc = nCc; rsB = rsC; reB = reC;
        nC = nD; nCc = nDc; rsC = rsD; reC = reD;
    }
}

extern "C" void kernel_launch(void* const* d_in, const int* in_sizes, int n_in,
                              void* d_out, int out_size, void* d_ws, size_t ws_size,
                              hipStream_t stream) {
    const float* x = (const float*)d_in[0];
    const int* ei  = (const int*)d_in[1];
    int E = in_sizes[1] / 2;
    int N = in_sizes[0] / CH;
    const int* esrc = ei;
    const int* edst = ei + E;

    const float* W1[3] = {(const float*)d_in[2], (const float*)d_in[6],  (const float*)d_in[10]};
    const float* B1[3] = {(const float*)d_in[3], (const float*)d_in[7],  (const float*)d_in[11]};
    const float* W2[3] = {(const float*)d_in[4], (const float*)d_in[8],  (const float*)d_in[12]};
    const float* B2[3] = {(const float*)d_in[5], (const float*)d_in[9],  (const float*)d_in[13]};

    char* base = (char*)d_ws;
    size_t off = 0;
    auto alloc = [&](size_t bytes) -> void* {
        void* p = base + off;
        off = (off + bytes + 255) & ~(size_t)255;
        return p;
    };
    int* counts    = (int*)alloc(sizeof(int) * (size_t)(N + 256));
    size_t zero_bytes = off;                       // counts must start at 0
    int* erank     = (int*)alloc(sizeof(int) * (size_t)E);
    int* row_ptr   = (int*)alloc(sizeof(int) * (size_t)(N + 1));
    int* blockSums = (int*)alloc(sizeof(int) * 256);
    int* blockOff  = (int*)alloc(sizeof(int) * 256);
    int* sed       = (int*)alloc(sizeof(int) * (size_t)E);
    f16* act       = (f16*)alloc(sizeof(f16) * (size_t)N * CH);
    f16* Pb        = (f16*)alloc(sizeof(f16) * (size_t)N * CH);
    f16* Qb        = (f16*)alloc(sizeof(f16) * (size_t)N * CH);
    f16* WcT       = (f16*)alloc(sizeof(f16) * 3 * 256 * CH);
    f16* W2T       = (f16*)alloc(sizeof(f16) * 3 * CH * CH);

    hipMemsetAsync(d_ws, 0, zero_bytes, stream);

    int gE = (E + 255) / 256;
    int gN = (N + 255) / 256;
    // fused: hist(+rank) + 3x weight prep (no cvt — layer-0 GEMM reads x directly)
    k_front<<<gE + 576, 256, 0, stream>>>(edst, counts, erank, E,
                                          W1[0], W2[0], W1[1], W2[1], W1[2], W2[2],
                                          WcT, W2T, gE);
    k_scan1<<<gN, 256, 0, stream>>>(counts, row_ptr, blockSums, N);
    k_scan2<<<1, 256, 0, stream>>>(blockSums, blockOff, gN);
    k_scan3<<<gN, 256, 0, stream>>>(row_ptr, blockOff, N);
    k_scatter<<<gE, 256, 0, stream>>>(esrc, edst, row_ptr, erank, sed, E);

    int gNode = 768;                               // 3 blocks/CU x 256 CU
    if (gNode > (N + 3) / 4) gNode = (N + 3) / 4;
    int nwv = gNode * 4;
    int gG1 = ((N + 255) / 256) * 4;               // nb-split x4 -> ~3 blocks/CU

    // layer 0: GEMM straight from f32 x (in-register cvt)
    k_gemm1x<<<gG1, 256, 0, stream>>>(x, WcT, B1[0], Pb, Qb, N);
    k_node<<<gNode, 256, 0, stream>>>(Pb, Qb, W2T, B2[0],
                                      row_ptr, sed, act, (float*)d_out, N, 1, nwv);
    for (int l = 1; l < 3; ++l) {
        k_gemm1<<<gG1, 256, 0, stream>>>(act, WcT + l * 256 * CH, B1[l], Pb, Qb, N);
        int flags = (l < 2) ? 1 : 2;
        k_node<<<gNode, 256, 0, stream>>>(Pb, Qb, W2T + l * CH * CH, B2[l],
                                          row_ptr, sed, act, (float*)d_out, N, flags, nwv);
    }
}

// Round 15
// 387.392 us; speedup vs baseline: 1.0257x; 1.0257x over previous
//
#include <hip/hip_runtime.h>

#define CH 128

typedef _Float16 f16;
typedef _Float16 f16x8 __attribute__((ext_vector_type(8)));
typedef float f32x4 __attribute__((ext_vector_type(4)));

__device__ __forceinline__ f32x4 mfma16(f16x8 a, f16x8 b, f32x4 c) {
    return __builtin_amdgcn_mfma_f32_16x16x32_f16(a, b, c, 0, 0, 0);
}

// ---------------- fused front: hist(+rank) + weight prep (3 layers) ----------------
__global__ __launch_bounds__(256) void k_front(const int* __restrict__ edst, int* __restrict__ counts,
                                               int* __restrict__ erank, int E,
                                               const float* __restrict__ W1a, const float* __restrict__ W2a,
                                               const float* __restrict__ W1b, const float* __restrict__ W2b,
                                               const float* __restrict__ W1c, const float* __restrict__ W2c,
                                               f16* __restrict__ WcT, f16* __restrict__ W2T,
                                               int gHist) {
    int bid = blockIdx.x;
    if (bid < gHist) {
        int e = bid * 256 + threadIdx.x;
        if (e < E) erank[e] = atomicAdd(&counts[edst[e]], 1);   // rank doubles as scatter cursor
    } else {
        int r = bid - gHist;
        int l = r / 192;
        const float* W1 = (l == 0) ? W1a : (l == 1) ? W1b : W1c;
        const float* W2 = (l == 0) ? W2a : (l == 1) ? W2b : W2c;
        f16* wct = WcT + l * 256 * CH;
        f16* w2t = W2T + l * CH * CH;
        int id = (r % 192) * 256 + threadIdx.x;   // 49152 per layer
        if (id < 32768) {
            int n = id >> 7, k = id & 127;
            float v;
            if (n < CH) v = W1[k * CH + n] - W1[(CH + k) * CH + n];
            else        v = W1[(CH + k) * CH + (n - CH)];
            wct[n * CH + k] = (f16)v;
        } else {
            int rr = id - 32768;
            int n = rr >> 7, k = rr & 127;
            w2t[n * CH + k] = (f16)W2[k * CH + n];
        }
    }
}

// ---------------- CSR scans + scatter (proven structure) ----------------
__global__ __launch_bounds__(256) void k_scan1(const int* __restrict__ counts, int* __restrict__ row_ptr,
                                               int* __restrict__ blockSums, int n) {
    __shared__ int s[256];
    int t = threadIdx.x;
    int i = blockIdx.x * 256 + t;
    s[t] = (i < n) ? counts[i] : 0;
    __syncthreads();
    for (int off = 1; off < 256; off <<= 1) {
        int x = (t >= off) ? s[t - off] : 0;
        __syncthreads();
        s[t] += x;
        __syncthreads();
    }
    if (i < n) row_ptr[i + 1] = s[t];
    if (t == 255) blockSums[blockIdx.x] = s[255];
}

__global__ __launch_bounds__(256) void k_scan2(const int* __restrict__ blockSums, int* __restrict__ blockOff, int nb) {
    __shared__ int s[256];
    int t = threadIdx.x;
    s[t] = (t < nb) ? blockSums[t] : 0;
    __syncthreads();
    for (int off = 1; off < 256; off <<= 1) {
        int x = (t >= off) ? s[t - off] : 0;
        __syncthreads();
        s[t] += x;
        __syncthreads();
    }
    blockOff[t] = (t == 0) ? 0 : s[t - 1];
}

__global__ __launch_bounds__(256) void k_scan3(int* __restrict__ row_ptr, const int* __restrict__ blockOff, int n) {
    int i = blockIdx.x * 256 + threadIdx.x;
    if (i < n) row_ptr[i + 1] += blockOff[blockIdx.x];
    if (blockIdx.x == 0 && threadIdx.x == 0) row_ptr[0] = 0;
}

// atomic-free scatter: pos = row_ptr[dst] + precomputed rank
__global__ __launch_bounds__(256) void k_scatter(const int* __restrict__ src, const int* __restrict__ dst,
                                                 const int* __restrict__ row_ptr, const int* __restrict__ erank,
                                                 int* __restrict__ sed, int E) {
    int e = blockIdx.x * 256 + threadIdx.x;
    if (e < E) {
        int pos = row_ptr[dst[e]] + erank[e];
        sed[pos] = src[e];
    }
}

// ---------------- layer-0 node GEMM: reads x as f32, converts in-register ----------------
__global__ __launch_bounds__(256) void k_gemm1x(const float* __restrict__ xf, const f16* __restrict__ WcT,
                                                const float* __restrict__ b1,
                                                f16* __restrict__ P, f16* __restrict__ Q, int nrows) {
    int t = threadIdx.x;
    int w = t >> 6, lane = t & 63;
    int m = lane & 15, q = lane >> 4;
    int rowbase = blockIdx.x * 256 + w * 64;
    f16x8 a[4][4];   // [row-tile][kk]
#pragma unroll
    for (int rt = 0; rt < 4; ++rt) {
        int rowc = min(rowbase + rt * 16 + m, nrows - 1);
        const float* xr = xf + (size_t)rowc * CH;
#pragma unroll
        for (int kk = 0; kk < 4; ++kk) {
            float4 v0 = *(const float4*)(xr + kk * 32 + q * 8);
            float4 v1 = *(const float4*)(xr + kk * 32 + q * 8 + 4);
            f16x8 h;
            h[0] = (f16)v0.x; h[1] = (f16)v0.y; h[2] = (f16)v0.z; h[3] = (f16)v0.w;
            h[4] = (f16)v1.x; h[5] = (f16)v1.y; h[6] = (f16)v1.z; h[7] = (f16)v1.w;
            a[rt][kk] = h;
        }
    }
#pragma unroll
    for (int nb = 0; nb < 16; ++nb) {
        f16x8 b[4];
#pragma unroll
        for (int kk = 0; kk < 4; ++kk)
            b[kk] = *(const f16x8*)(WcT + (nb * 16 + m) * CH + kk * 32 + q * 8);
        int col = nb * 16 + m;
        float bias = (nb < 8) ? b1[col] : 0.f;
#pragma unroll
        for (int rt = 0; rt < 4; ++rt) {
            f32x4 acc = {0.f, 0.f, 0.f, 0.f};
#pragma unroll
            for (int kk = 0; kk < 4; ++kk) acc = mfma16(a[rt][kk], b[kk], acc);
#pragma unroll
            for (int r = 0; r < 4; ++r) {
                int ro = rowbase + rt * 16 + q * 4 + r;
                if (ro < nrows) {
                    float v = acc[r] + bias;
                    if (nb < 8) P[(size_t)ro * CH + col] = (f16)v;
                    else        Q[(size_t)ro * CH + (col - CH)] = (f16)v;
                }
            }
        }
    }
}

// ---------------- node GEMM (layers 1,2): [P|Q] = act @ WcT^T, P gets +b1 ----------------
__global__ __launch_bounds__(256) void k_gemm1(const f16* __restrict__ act, const f16* __restrict__ WcT,
                                               const float* __restrict__ b1,
                                               f16* __restrict__ P, f16* __restrict__ Q, int nrows) {
    int t = threadIdx.x;
    int w = t >> 6, lane = t & 63;
    int m = lane & 15, q = lane >> 4;
    int rowbase = blockIdx.x * 256 + w * 64;
    f16x8 a[4][4];   // [row-tile][kk]
#pragma unroll
    for (int rt = 0; rt < 4; ++rt) {
        int rowc = min(rowbase + rt * 16 + m, nrows - 1);
#pragma unroll
        for (int kk = 0; kk < 4; ++kk)
            a[rt][kk] = *(const f16x8*)(act + (size_t)rowc * CH + kk * 32 + q * 8);
    }
#pragma unroll
    for (int nb = 0; nb < 16; ++nb) {
        f16x8 b[4];
#pragma unroll
        for (int kk = 0; kk < 4; ++kk)
            b[kk] = *(const f16x8*)(WcT + (nb * 16 + m) * CH + kk * 32 + q * 8);
        int col = nb * 16 + m;
        float bias = (nb < 8) ? b1[col] : 0.f;
#pragma unroll
        for (int rt = 0; rt < 4; ++rt) {
            f32x4 acc = {0.f, 0.f, 0.f, 0.f};
#pragma unroll
            for (int kk = 0; kk < 4; ++kk) acc = mfma16(a[rt][kk], b[kk], acc);
#pragma unroll
            for (int r = 0; r < 4; ++r) {
                int ro = rowbase + rt * 16 + q * 4 + r;
                if (ro < nrows) {
                    float v = acc[r] + bias;
                    if (nb < 8) P[(size_t)ro * CH + col] = (f16)v;
                    else        Q[(size_t)ro * CH + (col - CH)] = (f16)v;
                }
            }
        }
    }
}

// ---------------- per-node edge GEMM + register max: 1 wave = 1 dst node ----------------
// v9 = v8 (63.5us proven) with the node loop unrolled x2 over two register sets
// (S0/S1 alternate consume/fill roles) — deletes the per-iteration pipeline-rotate
// copies (8 f16x8 + 10 scalars = ~70cy/iter of pure VALU). Peak liveness unchanged.
// flags: bit0 relu out, bit1 fp32 final out.
__global__ __launch_bounds__(256, 3)
void k_node(const f16* __restrict__ P, const f16* __restrict__ Q,
            const f16* __restrict__ W2Tg, const float* __restrict__ b2,
            const int* __restrict__ row_ptr, const int* __restrict__ sed,
            f16* __restrict__ act_out, float* __restrict__ final_out,
            int n_nodes, int flags, int nwv) {
    __shared__ __align__(16) f16 w2lds[8 * 4 * 64 * 8];   // 32 KB, fragment order

    int t = threadIdx.x;
    int w = t >> 6, lane = t & 63;
    int m = lane & 15, q = lane >> 4;

#pragma unroll
    for (int i = t; i < 2048; i += 256) {
        int nb = i >> 8, rem = i & 255, kk = rem >> 6, ln = rem & 63;
        int mm = ln & 15, qq = ln >> 4;
        *(f16x8*)&w2lds[i * 8] = *(const f16x8*)(W2Tg + (size_t)(nb * 16 + mm) * CH + kk * 32 + qq * 8);
    }
    __syncthreads();

    float biasA = b2[lane], biasB = b2[lane + 64];
    const f16x8 z8 = {};
    const f32x4 z4 = {0.f, 0.f, 0.f, 0.f};

    auto mkAf = [&](const f16x8* pf, f16x8* qs) {
#pragma unroll
        for (int kk = 0; kk < 4; ++kk) qs[kk] = __builtin_elementwise_max(pf[kk] + qs[kk], z8);
    };
    auto tile1 = [&](const f16x8* af, float* rmax) {
        unsigned wo = 0;
        asm volatile("" : "+v"(wo));              // per-call opacity: no LICM hoist of LDS reads
        const f16* wb = w2lds + wo + (size_t)lane * 8;
#pragma unroll
        for (int nb = 0; nb < 8; ++nb) {
            f32x4 a0 = z4;
#pragma unroll
            for (int kk = 0; kk < 4; ++kk) {
                f16x8 bq = *(const f16x8*)(wb + (nb * 4 + kk) * 512);
                a0 = mfma16(af[kk], bq, a0);
            }
            rmax[nb] = fmaxf(fmaxf(fmaxf(a0[0], a0[1]), fmaxf(a0[2], a0[3])), rmax[nb]);
        }
    };
    auto tile2 = [&](const f16x8* af0, const f16x8* af1, float* rmax) {
        unsigned wo = 0;
        asm volatile("" : "+v"(wo));
        const f16* wb = w2lds + wo + (size_t)lane * 8;
#pragma unroll
        for (int nb = 0; nb < 8; ++nb) {
            f32x4 a0 = z4, a1 = z4;
#pragma unroll
            for (int kk = 0; kk < 4; ++kk) {
                f16x8 bq = *(const f16x8*)(wb + (nb * 4 + kk) * 512);
                a0 = mfma16(af0[kk], bq, a0);
                a1 = mfma16(af1[kk], bq, a1);
            }
            a0 = __builtin_elementwise_max(a0, a1);
            rmax[nb] = fmaxf(fmaxf(fmaxf(a0[0], a0[1]), fmaxf(a0[2], a0[3])), rmax[nb]);
        }
    };
    // compute + store for one node; af0/qs1 consumed, next-node data untouched
    auto computeNode = [&](int node, int rs, int re, int idx1,
                           f16x8* pf, f16x8* qs0) {
        float o0 = 0.f, o1 = 0.f;
        if (re > rs) {
            f16x8 qs1[4] = {};
            if (re - rs > 16) {
#pragma unroll
                for (int kk = 0; kk < 4; ++kk)
                    qs1[kk] = *(const f16x8*)(Q + (size_t)idx1 * CH + kk * 32 + q * 8);
            }
            float rmax[8];
#pragma unroll
            for (int nb = 0; nb < 8; ++nb) rmax[nb] = -3.4e38f;
            mkAf(pf, qs0);
            if (re - rs > 16) {
                mkAf(pf, qs1);
                tile2(qs0, qs1, rmax);
            } else {
                tile1(qs0, rmax);
            }
            for (int tb = rs + 32; tb < re; tb += 16) {     // deg>32: rare serial tail
                int s2 = sed[min(tb + m, re - 1)];
                f16x8 qx[4];
#pragma unroll
                for (int kk = 0; kk < 4; ++kk)
                    qx[kk] = *(const f16x8*)(Q + (size_t)s2 * CH + kk * 32 + q * 8);
                mkAf(pf, qx);
                tile1(qx, rmax);
            }
#pragma unroll
            for (int nb = 0; nb < 8; ++nb) {
                float v = rmax[nb];
                v = fmaxf(v, __shfl_xor(v, 16));
                v = fmaxf(v, __shfl_xor(v, 32));
                rmax[nb] = v;
            }
            float vA = (q & 2) ? ((q & 1) ? rmax[3] : rmax[2]) : ((q & 1) ? rmax[1] : rmax[0]);
            float vB = (q & 2) ? ((q & 1) ? rmax[7] : rmax[6]) : ((q & 1) ? rmax[5] : rmax[4]);
            o0 = vA + biasA;
            o1 = vB + biasB;
            if (flags & 1) { o0 = fmaxf(o0, 0.f); o1 = fmaxf(o1, 0.f); }
        }
        if (flags & 2) {
            float* orow = final_out + (size_t)node * CH;
            orow[lane] = o0; orow[lane + 64] = o1;
        } else {
            f16* orow = act_out + (size_t)node * CH;
            orow[lane] = (f16)o0; orow[lane + 64] = (f16)o1;
        }
    };

    int n0 = blockIdx.x * 4 + w;
    if (n0 >= n_nodes) return;
    int nmax = n_nodes - 1;

    // two alternating state sets; roles swap each half-iteration (no rotate copies)
    int nA = n0;
    int rsA = row_ptr[nA], reA = row_ptr[nA + 1];
    int nB = nA + nwv; int nBc = min(nB, nmax);
    int rsB = row_ptr[nBc], reB = row_ptr[nBc + 1];

    int lA = (reA > rsA) ? reA - 1 : 0;
    int idx0A = sed[min(rsA + m, lA)];
    int idx1A = sed[min(rsA + 16 + m, lA)];
    int lB = (reB > rsB) ? reB - 1 : 0;
    int idx0B = sed[min(rsB + m, lB)];
    int idx1B = sed[min(rsB + 16 + m, lB)];

    f16x8 pfA[4], qsA[4], pfB[4], qsB[4];
#pragma unroll
    for (int kk = 0; kk < 4; ++kk) {
        pfA[kk] = *(const f16x8*)(P + (size_t)nA * CH + kk * 32 + q * 8);
        qsA[kk] = *(const f16x8*)(Q + (size_t)idx0A * CH + kk * 32 + q * 8);
    }

    while (true) {
        // --- half 1: fill set B's data (node nB), compute set A (node nA) ---
#pragma unroll
        for (int kk = 0; kk < 4; ++kk) {
            qsB[kk] = *(const f16x8*)(Q + (size_t)idx0B * CH + kk * 32 + q * 8);
            pfB[kk] = *(const f16x8*)(P + (size_t)nBc * CH + kk * 32 + q * 8);
        }
        int nC = nB + nwv; int nCc = min(nC, nmax);
        int rsC = row_ptr[nCc], reC = row_ptr[nCc + 1];
        int lC = (reC > rsC) ? reC - 1 : 0;
        int idx0C = sed[min(rsC + m, lC)];
        int idx1C = sed[min(rsC + 16 + m, lC)];

        computeNode(nA, rsA, reA, idx1A, pfA, qsA);

        if (nB >= n_nodes) break;
        // roles swap: A-state now free for node nC
        nA = nC; rsA = rsC; reA = reC; idx0A = idx0C; idx1A = idx1C;

        // --- half 2: fill set A's data (node nC), compute set B (node nB) ---
#pragma unroll
        for (int kk = 0; kk < 4; ++kk) {
            qsA[kk] = *(const f16x8*)(Q + (size_t)idx0A * CH + kk * 32 + q * 8);
            pfA[kk] = *(const f16x8*)(P + (size_t)min(nA, nmax) * CH + kk * 32 + q * 8);
        }
        int nD = nA + nwv; int nDc = min(nD, nmax);
        int rsD = row_ptr[nDc], reD = row_ptr[nDc + 1];
        int lD = (reD > rsD) ? reD - 1 : 0;
        int idx0D = sed[min(rsD + m, lD)];
        int idx1D = sed[min(rsD + 16 + m, lD)];

        computeNode(nBc, rsB, reB, idx1B, pfB, qsB);

        if (nA >= n_nodes) break;
        nB = nD; nBc = nDc; rsB = rsD; reB = reD; idx0B = idx0D; idx1B = idx1D;
    }
}

extern "C" void kernel_launch(void* const* d_in, const int* in_sizes, int n_in,
                              void* d_out, int out_size, void* d_ws, size_t ws_size,
                              hipStream_t stream) {
    const float* x = (const float*)d_in[0];
    const int* ei  = (const int*)d_in[1];
    int E = in_sizes[1] / 2;
    int N = in_sizes[0] / CH;
    const int* esrc = ei;
    const int* edst = ei + E;

    const float* W1[3] = {(const float*)d_in[2], (const float*)d_in[6],  (const float*)d_in[10]};
    const float* B1[3] = {(const float*)d_in[3], (const float*)d_in[7],  (const float*)d_in[11]};
    const float* W2[3] = {(const float*)d_in[4], (const float*)d_in[8],  (const float*)d_in[12]};
    const float* B2[3] = {(const float*)d_in[5], (const float*)d_in[9],  (const float*)d_in[13]};

    char* base = (char*)d_ws;
    size_t off = 0;
    auto alloc = [&](size_t bytes) -> void* {
        void* p = base + off;
        off = (off + bytes + 255) & ~(size_t)255;
        return p;
    };
    int* counts    = (int*)alloc(sizeof(int) * (size_t)(N + 256));
    size_t zero_bytes = off;                       // counts must start at 0
    int* erank     = (int*)alloc(sizeof(int) * (size_t)E);
    int* row_ptr   = (int*)alloc(sizeof(int) * (size_t)(N + 1));
    int* blockSums = (int*)alloc(sizeof(int) * 256);
    int* blockOff  = (int*)alloc(sizeof(int) * 256);
    int* sed       = (int*)alloc(sizeof(int) * (size_t)E);
    f16* act       = (f16*)alloc(sizeof(f16) * (size_t)N * CH);
    f16* Pb        = (f16*)alloc(sizeof(f16) * (size_t)N * CH);
    f16* Qb        = (f16*)alloc(sizeof(f16) * (size_t)N * CH);
    f16* WcT       = (f16*)alloc(sizeof(f16) * 3 * 256 * CH);
    f16* W2T       = (f16*)alloc(sizeof(f16) * 3 * CH * CH);

    hipMemsetAsync(d_ws, 0, zero_bytes, stream);

    int gE = (E + 255) / 256;
    int gN = (N + 255) / 256;
    // fused: hist(+rank) + 3x weight prep (no cvt — layer-0 GEMM reads x directly)
    k_front<<<gE + 576, 256, 0, stream>>>(edst, counts, erank, E,
                                          W1[0], W2[0], W1[1], W2[1], W1[2], W2[2],
                                          WcT, W2T, gE);
    k_scan1<<<gN, 256, 0, stream>>>(counts, row_ptr, blockSums, N);
    k_scan2<<<1, 256, 0, stream>>>(blockSums, blockOff, gN);
    k_scan3<<<gN, 256, 0, stream>>>(row_ptr, blockOff, N);
    k_scatter<<<gE, 256, 0, stream>>>(esrc, edst, row_ptr, erank, sed, E);

    int gNode = 768;                               // 3 blocks/CU x 256 CU
    if (gNode > (N + 3) / 4) gNode = (N + 3) / 4;
    int nwv = gNode * 4;
    int gG1 = (N + 255) / 256;

    // layer 0: GEMM straight from f32 x (in-register cvt)
    k_gemm1x<<<gG1, 256, 0, stream>>>(x, WcT, B1[0], Pb, Qb, N);
    k_node<<<gNode, 256, 0, stream>>>(Pb, Qb, W2T, B2[0],
                                      row_ptr, sed, act, (float*)d_out, N, 1, nwv);
    for (int l = 1; l < 3; ++l) {
        k_gemm1<<<gG1, 256, 0, stream>>>(act, WcT + l * 256 * CH, B1[l], Pb, Qb, N);
        int flags = (l < 2) ? 1 : 2;
        k_node<<<gNode, 256, 0, stream>>>(Pb, Qb, W2T + l * CH * CH, B2[l],
                                          row_ptr, sed, act, (float*)d_out, N, flags, nwv);
    }
}

// Round 16
// 383.132 us; speedup vs baseline: 1.0371x; 1.0111x over previous
//
#include <hip/hip_runtime.h>

#define CH 128

typedef _Float16 f16;
typedef _Float16 f16x8 __attribute__((ext_vector_type(8)));
typedef float f32x4 __attribute__((ext_vector_type(4)));

__device__ __forceinline__ f32x4 mfma16(f16x8 a, f16x8 b, f32x4 c) {
    return __builtin_amdgcn_mfma_f32_16x16x32_f16(a, b, c, 0, 0, 0);
}

// ---------------- fused front: hist(+rank) + weight prep (3 layers) ----------------
__global__ __launch_bounds__(256) void k_front(const int* __restrict__ edst, int* __restrict__ counts,
                                               int* __restrict__ erank, int E,
                                               const float* __restrict__ W1a, const float* __restrict__ W2a,
                                               const float* __restrict__ W1b, const float* __restrict__ W2b,
                                               const float* __restrict__ W1c, const float* __restrict__ W2c,
                                               f16* __restrict__ WcT, f16* __restrict__ W2T,
                                               int gHist) {
    int bid = blockIdx.x;
    if (bid < gHist) {
        int e = bid * 256 + threadIdx.x;
        if (e < E) erank[e] = atomicAdd(&counts[edst[e]], 1);   // rank doubles as scatter cursor
    } else {
        int r = bid - gHist;
        int l = r / 192;
        const float* W1 = (l == 0) ? W1a : (l == 1) ? W1b : W1c;
        const float* W2 = (l == 0) ? W2a : (l == 1) ? W2b : W2c;
        f16* wct = WcT + l * 256 * CH;
        f16* w2t = W2T + l * CH * CH;
        int id = (r % 192) * 256 + threadIdx.x;   // 49152 per layer
        if (id < 32768) {
            int n = id >> 7, k = id & 127;
            float v;
            if (n < CH) v = W1[k * CH + n] - W1[(CH + k) * CH + n];
            else        v = W1[(CH + k) * CH + (n - CH)];
            wct[n * CH + k] = (f16)v;
        } else {
            int rr = id - 32768;
            int n = rr >> 7, k = rr & 127;
            w2t[n * CH + k] = (f16)W2[k * CH + n];
        }
    }
}

// ---------------- CSR scans + scatter (proven structure) ----------------
__global__ __launch_bounds__(256) void k_scan1(const int* __restrict__ counts, int* __restrict__ row_ptr,
                                               int* __restrict__ blockSums, int n) {
    __shared__ int s[256];
    int t = threadIdx.x;
    int i = blockIdx.x * 256 + t;
    s[t] = (i < n) ? counts[i] : 0;
    __syncthreads();
    for (int off = 1; off < 256; off <<= 1) {
        int x = (t >= off) ? s[t - off] : 0;
        __syncthreads();
        s[t] += x;
        __syncthreads();
    }
    if (i < n) row_ptr[i + 1] = s[t];
    if (t == 255) blockSums[blockIdx.x] = s[255];
}

__global__ __launch_bounds__(256) void k_scan2(const int* __restrict__ blockSums, int* __restrict__ blockOff, int nb) {
    __shared__ int s[256];
    int t = threadIdx.x;
    s[t] = (t < nb) ? blockSums[t] : 0;
    __syncthreads();
    for (int off = 1; off < 256; off <<= 1) {
        int x = (t >= off) ? s[t - off] : 0;
        __syncthreads();
        s[t] += x;
        __syncthreads();
    }
    blockOff[t] = (t == 0) ? 0 : s[t - 1];
}

__global__ __launch_bounds__(256) void k_scan3(int* __restrict__ row_ptr, const int* __restrict__ blockOff, int n) {
    int i = blockIdx.x * 256 + threadIdx.x;
    if (i < n) row_ptr[i + 1] += blockOff[blockIdx.x];
    if (blockIdx.x == 0 && threadIdx.x == 0) row_ptr[0] = 0;
}

// atomic-free scatter: pos = row_ptr[dst] + precomputed rank
__global__ __launch_bounds__(256) void k_scatter(const int* __restrict__ src, const int* __restrict__ dst,
                                                 const int* __restrict__ row_ptr, const int* __restrict__ erank,
                                                 int* __restrict__ sed, int E) {
    int e = blockIdx.x * 256 + threadIdx.x;
    if (e < E) {
        int pos = row_ptr[dst[e]] + erank[e];
        sed[pos] = src[e];
    }
}

// ---------------- layer-0 node GEMM: reads x as f32, converts in-register ----------------
__global__ __launch_bounds__(256) void k_gemm1x(const float* __restrict__ xf, const f16* __restrict__ WcT,
                                                const float* __restrict__ b1,
                                                f16* __restrict__ P, f16* __restrict__ Q, int nrows) {
    int t = threadIdx.x;
    int w = t >> 6, lane = t & 63;
    int m = lane & 15, q = lane >> 4;
    int rowbase = blockIdx.x * 256 + w * 64;
    f16x8 a[4][4];   // [row-tile][kk]
#pragma unroll
    for (int rt = 0; rt < 4; ++rt) {
        int rowc = min(rowbase + rt * 16 + m, nrows - 1);
        const float* xr = xf + (size_t)rowc * CH;
#pragma unroll
        for (int kk = 0; kk < 4; ++kk) {
            float4 v0 = *(const float4*)(xr + kk * 32 + q * 8);
            float4 v1 = *(const float4*)(xr + kk * 32 + q * 8 + 4);
            f16x8 h;
            h[0] = (f16)v0.x; h[1] = (f16)v0.y; h[2] = (f16)v0.z; h[3] = (f16)v0.w;
            h[4] = (f16)v1.x; h[5] = (f16)v1.y; h[6] = (f16)v1.z; h[7] = (f16)v1.w;
            a[rt][kk] = h;
        }
    }
#pragma unroll
    for (int nb = 0; nb < 16; ++nb) {
        f16x8 b[4];
#pragma unroll
        for (int kk = 0; kk < 4; ++kk)
            b[kk] = *(const f16x8*)(WcT + (nb * 16 + m) * CH + kk * 32 + q * 8);
        int col = nb * 16 + m;
        float bias = (nb < 8) ? b1[col] : 0.f;
#pragma unroll
        for (int rt = 0; rt < 4; ++rt) {
            f32x4 acc = {0.f, 0.f, 0.f, 0.f};
#pragma unroll
            for (int kk = 0; kk < 4; ++kk) acc = mfma16(a[rt][kk], b[kk], acc);
#pragma unroll
            for (int r = 0; r < 4; ++r) {
                int ro = rowbase + rt * 16 + q * 4 + r;
                if (ro < nrows) {
                    float v = acc[r] + bias;
                    if (nb < 8) P[(size_t)ro * CH + col] = (f16)v;
                    else        Q[(size_t)ro * CH + (col - CH)] = (f16)v;
                }
            }
        }
    }
}

// ---------------- node GEMM (layers 1,2): [P|Q] = act @ WcT^T, P gets +b1 ----------------
__global__ __launch_bounds__(256) void k_gemm1(const f16* __restrict__ act, const f16* __restrict__ WcT,
                                               const float* __restrict__ b1,
                                               f16* __restrict__ P, f16* __restrict__ Q, int nrows) {
    int t = threadIdx.x;
    int w = t >> 6, lane = t & 63;
    int m = lane & 15, q = lane >> 4;
    int rowbase = blockIdx.x * 256 + w * 64;
    f16x8 a[4][4];   // [row-tile][kk]
#pragma unroll
    for (int rt = 0; rt < 4; ++rt) {
        int rowc = min(rowbase + rt * 16 + m, nrows - 1);
#pragma unroll
        for (int kk = 0; kk < 4; ++kk)
            a[rt][kk] = *(const f16x8*)(act + (size_t)rowc * CH + kk * 32 + q * 8);
    }
#pragma unroll
    for (int nb = 0; nb < 16; ++nb) {
        f16x8 b[4];
#pragma unroll
        for (int kk = 0; kk < 4; ++kk)
            b[kk] = *(const f16x8*)(WcT + (nb * 16 + m) * CH + kk * 32 + q * 8);
        int col = nb * 16 + m;
        float bias = (nb < 8) ? b1[col] : 0.f;
#pragma unroll
        for (int rt = 0; rt < 4; ++rt) {
            f32x4 acc = {0.f, 0.f, 0.f, 0.f};
#pragma unroll
            for (int kk = 0; kk < 4; ++kk) acc = mfma16(a[rt][kk], b[kk], acc);
#pragma unroll
            for (int r = 0; r < 4; ++r) {
                int ro = rowbase + rt * 16 + q * 4 + r;
                if (ro < nrows) {
                    float v = acc[r] + bias;
                    if (nb < 8) P[(size_t)ro * CH + col] = (f16)v;
                    else        Q[(size_t)ro * CH + (col - CH)] = (f16)v;
                }
            }
        }
    }
}

// ---------------- per-node edge GEMM + register max: 1 wave = 1 dst node ----------------
// v10 = v9 (62.6us proven) + s_setprio(1) around the MFMA clusters (T5). Mechanism:
// 12 independent waves/CU alternate gather-issue and MFMA phases; raising priority
// during the MFMA cluster lets the matrix pipe drain instead of interleaving with
// other waves' VMEM issue. 0 registers, 2 SALU per tile pass. (T5 was null on
// barrier-lockstep GEMM but +4-7% on independent-wave attn — k_node is the latter.)
// flags: bit0 relu out, bit1 fp32 final out.
__global__ __launch_bounds__(256, 3)
void k_node(const f16* __restrict__ P, const f16* __restrict__ Q,
            const f16* __restrict__ W2Tg, const float* __restrict__ b2,
            const int* __restrict__ row_ptr, const int* __restrict__ sed,
            f16* __restrict__ act_out, float* __restrict__ final_out,
            int n_nodes, int flags, int nwv) {
    __shared__ __align__(16) f16 w2lds[8 * 4 * 64 * 8];   // 32 KB, fragment order

    int t = threadIdx.x;
    int w = t >> 6, lane = t & 63;
    int m = lane & 15, q = lane >> 4;

#pragma unroll
    for (int i = t; i < 2048; i += 256) {
        int nb = i >> 8, rem = i & 255, kk = rem >> 6, ln = rem & 63;
        int mm = ln & 15, qq = ln >> 4;
        *(f16x8*)&w2lds[i * 8] = *(const f16x8*)(W2Tg + (size_t)(nb * 16 + mm) * CH + kk * 32 + qq * 8);
    }
    __syncthreads();

    float biasA = b2[lane], biasB = b2[lane + 64];
    const f16x8 z8 = {};
    const f32x4 z4 = {0.f, 0.f, 0.f, 0.f};

    auto mkAf = [&](const f16x8* pf, f16x8* qs) {
#pragma unroll
        for (int kk = 0; kk < 4; ++kk) qs[kk] = __builtin_elementwise_max(pf[kk] + qs[kk], z8);
    };
    auto tile1 = [&](const f16x8* af, float* rmax) {
        unsigned wo = 0;
        asm volatile("" : "+v"(wo));              // per-call opacity: no LICM hoist of LDS reads
        const f16* wb = w2lds + wo + (size_t)lane * 8;
        __builtin_amdgcn_s_setprio(1);
#pragma unroll
        for (int nb = 0; nb < 8; ++nb) {
            f32x4 a0 = z4;
#pragma unroll
            for (int kk = 0; kk < 4; ++kk) {
                f16x8 bq = *(const f16x8*)(wb + (nb * 4 + kk) * 512);
                a0 = mfma16(af[kk], bq, a0);
            }
            rmax[nb] = fmaxf(fmaxf(fmaxf(a0[0], a0[1]), fmaxf(a0[2], a0[3])), rmax[nb]);
        }
        __builtin_amdgcn_s_setprio(0);
    };
    auto tile2 = [&](const f16x8* af0, const f16x8* af1, float* rmax) {
        unsigned wo = 0;
        asm volatile("" : "+v"(wo));
        const f16* wb = w2lds + wo + (size_t)lane * 8;
        __builtin_amdgcn_s_setprio(1);
#pragma unroll
        for (int nb = 0; nb < 8; ++nb) {
            f32x4 a0 = z4, a1 = z4;
#pragma unroll
            for (int kk = 0; kk < 4; ++kk) {
                f16x8 bq = *(const f16x8*)(wb + (nb * 4 + kk) * 512);
                a0 = mfma16(af0[kk], bq, a0);
                a1 = mfma16(af1[kk], bq, a1);
            }
            a0 = __builtin_elementwise_max(a0, a1);
            rmax[nb] = fmaxf(fmaxf(fmaxf(a0[0], a0[1]), fmaxf(a0[2], a0[3])), rmax[nb]);
        }
        __builtin_amdgcn_s_setprio(0);
    };
    // compute + store for one node; qs0 consumed, next-node data untouched
    auto computeNode = [&](int node, int rs, int re, int idx1,
                           f16x8* pf, f16x8* qs0) {
        float o0 = 0.f, o1 = 0.f;
        if (re > rs) {
            f16x8 qs1[4] = {};
            if (re - rs > 16) {
#pragma unroll
                for (int kk = 0; kk < 4; ++kk)
                    qs1[kk] = *(const f16x8*)(Q + (size_t)idx1 * CH + kk * 32 + q * 8);
            }
            float rmax[8];
#pragma unroll
            for (int nb = 0; nb < 8; ++nb) rmax[nb] = -3.4e38f;
            mkAf(pf, qs0);
            if (re - rs > 16) {
                mkAf(pf, qs1);
                tile2(qs0, qs1, rmax);
            } else {
                tile1(qs0, rmax);
            }
            for (int tb = rs + 32; tb < re; tb += 16) {     // deg>32: rare serial tail
                int s2 = sed[min(tb + m, re - 1)];
                f16x8 qx[4];
#pragma unroll
                for (int kk = 0; kk < 4; ++kk)
                    qx[kk] = *(const f16x8*)(Q + (size_t)s2 * CH + kk * 32 + q * 8);
                mkAf(pf, qx);
                tile1(qx, rmax);
            }
#pragma unroll
            for (int nb = 0; nb < 8; ++nb) {
                float v = rmax[nb];
                v = fmaxf(v, __shfl_xor(v, 16));
                v = fmaxf(v, __shfl_xor(v, 32));
                rmax[nb] = v;
            }
            float vA = (q & 2) ? ((q & 1) ? rmax[3] : rmax[2]) : ((q & 1) ? rmax[1] : rmax[0]);
            float vB = (q & 2) ? ((q & 1) ? rmax[7] : rmax[6]) : ((q & 1) ? rmax[5] : rmax[4]);
            o0 = vA + biasA;
            o1 = vB + biasB;
            if (flags & 1) { o0 = fmaxf(o0, 0.f); o1 = fmaxf(o1, 0.f); }
        }
        if (flags & 2) {
            float* orow = final_out + (size_t)node * CH;
            orow[lane] = o0; orow[lane + 64] = o1;
        } else {
            f16* orow = act_out + (size_t)node * CH;
            orow[lane] = (f16)o0; orow[lane + 64] = (f16)o1;
        }
    };

    int n0 = blockIdx.x * 4 + w;
    if (n0 >= n_nodes) return;
    int nmax = n_nodes - 1;

    // two alternating state sets; roles swap each half-iteration (no rotate copies)
    int nA = n0;
    int rsA = row_ptr[nA], reA = row_ptr[nA + 1];
    int nB = nA + nwv; int nBc = min(nB, nmax);
    int rsB = row_ptr[nBc], reB = row_ptr[nBc + 1];

    int lA = (reA > rsA) ? reA - 1 : 0;
    int idx0A = sed[min(rsA + m, lA)];
    int idx1A = sed[min(rsA + 16 + m, lA)];
    int lB = (reB > rsB) ? reB - 1 : 0;
    int idx0B = sed[min(rsB + m, lB)];
    int idx1B = sed[min(rsB + 16 + m, lB)];

    f16x8 pfA[4], qsA[4], pfB[4], qsB[4];
#pragma unroll
    for (int kk = 0; kk < 4; ++kk) {
        pfA[kk] = *(const f16x8*)(P + (size_t)nA * CH + kk * 32 + q * 8);
        qsA[kk] = *(const f16x8*)(Q + (size_t)idx0A * CH + kk * 32 + q * 8);
    }

    while (true) {
        // --- half 1: fill set B's data (node nB), compute set A (node nA) ---
#pragma unroll
        for (int kk = 0; kk < 4; ++kk) {
            qsB[kk] = *(const f16x8*)(Q + (size_t)idx0B * CH + kk * 32 + q * 8);
            pfB[kk] = *(const f16x8*)(P + (size_t)nBc * CH + kk * 32 + q * 8);
        }
        int nC = nB + nwv; int nCc = min(nC, nmax);
        int rsC = row_ptr[nCc], reC = row_ptr[nCc + 1];
        int lC = (reC > rsC) ? reC - 1 : 0;
        int idx0C = sed[min(rsC + m, lC)];
        int idx1C = sed[min(rsC + 16 + m, lC)];

        computeNode(nA, rsA, reA, idx1A, pfA, qsA);

        if (nB >= n_nodes) break;
        // roles swap: A-state now free for node nC
        nA = nC; rsA = rsC; reA = reC; idx0A = idx0C; idx1A = idx1C;

        // --- half 2: fill set A's data (node nC), compute set B (node nB) ---
#pragma unroll
        for (int kk = 0; kk < 4; ++kk) {
            qsA[kk] = *(const f16x8*)(Q + (size_t)idx0A * CH + kk * 32 + q * 8);
            pfA[kk] = *(const f16x8*)(P + (size_t)min(nA, nmax) * CH + kk * 32 + q * 8);
        }
        int nD = nA + nwv; int nDc = min(nD, nmax);
        int rsD = row_ptr[nDc], reD = row_ptr[nDc + 1];
        int lD = (reD > rsD) ? reD - 1 : 0;
        int idx0D = sed[min(rsD + m, lD)];
        int idx1D = sed[min(rsD + 16 + m, lD)];

        computeNode(nBc, rsB, reB, idx1B, pfB, qsB);

        if (nA >= n_nodes) break;
        nB = nD; nBc = nDc; rsB = rsD; reB = reD; idx0B = idx0D; idx1B = idx1D;
    }
}

extern "C" void kernel_launch(void* const* d_in, const int* in_sizes, int n_in,
                              void* d_out, int out_size, void* d_ws, size_t ws_size,
                              hipStream_t stream) {
    const float* x = (const float*)d_in[0];
    const int* ei  = (const int*)d_in[1];
    int E = in_sizes[1] / 2;
    int N = in_sizes[0] / CH;
    const int* esrc = ei;
    const int* edst = ei + E;

    const float* W1[3] = {(const float*)d_in[2], (const float*)d_in[6],  (const float*)d_in[10]};
    const float* B1[3] = {(const float*)d_in[3], (const float*)d_in[7],  (const float*)d_in[11]};
    const float* W2[3] = {(const float*)d_in[4], (const float*)d_in[8],  (const float*)d_in[12]};
    const float* B2[3] = {(const float*)d_in[5], (const float*)d_in[9],  (const float*)d_in[13]};

    char* base = (char*)d_ws;
    size_t off = 0;
    auto alloc = [&](size_t bytes) -> void* {
        void* p = base + off;
        off = (off + bytes + 255) & ~(size_t)255;
        return p;
    };
    int* counts    = (int*)alloc(sizeof(int) * (size_t)(N + 256));
    size_t zero_bytes = off;                       // counts must start at 0
    int* erank     = (int*)alloc(sizeof(int) * (size_t)E);
    int* row_ptr   = (int*)alloc(sizeof(int) * (size_t)(N + 1));
    int* blockSums = (int*)alloc(sizeof(int) * 256);
    int* blockOff  = (int*)alloc(sizeof(int) * 256);
    int* sed       = (int*)alloc(sizeof(int) * (size_t)E);
    f16* act       = (f16*)alloc(sizeof(f16) * (size_t)N * CH);
    f16* Pb        = (f16*)alloc(sizeof(f16) * (size_t)N * CH);
    f16* Qb        = (f16*)alloc(sizeof(f16) * (size_t)N * CH);
    f16* WcT       = (f16*)alloc(sizeof(f16) * 3 * 256 * CH);
    f16* W2T       = (f16*)alloc(sizeof(f16) * 3 * CH * CH);

    hipMemsetAsync(d_ws, 0, zero_bytes, stream);

    int gE = (E + 255) / 256;
    int gN = (N + 255) / 256;
    // fused: hist(+rank) + 3x weight prep (no cvt — layer-0 GEMM reads x directly)
    k_front<<<gE + 576, 256, 0, stream>>>(edst, counts, erank, E,
                                          W1[0], W2[0], W1[1], W2[1], W1[2], W2[2],
                                          WcT, W2T, gE);
    k_scan1<<<gN, 256, 0, stream>>>(counts, row_ptr, blockSums, N);
    k_scan2<<<1, 256, 0, stream>>>(blockSums, blockOff, gN);
    k_scan3<<<gN, 256, 0, stream>>>(row_ptr, blockOff, N);
    k_scatter<<<gE, 256, 0, stream>>>(esrc, edst, row_ptr, erank, sed, E);

    int gNode = 768;                               // 3 blocks/CU x 256 CU
    if (gNode > (N + 3) / 4) gNode = (N + 3) / 4;
    int nwv = gNode * 4;
    int gG1 = (N + 255) / 256;

    // layer 0: GEMM straight from f32 x (in-register cvt)
    k_gemm1x<<<gG1, 256, 0, stream>>>(x, WcT, B1[0], Pb, Qb, N);
    k_node<<<gNode, 256, 0, stream>>>(Pb, Qb, W2T, B2[0],
                                      row_ptr, sed, act, (float*)d_out, N, 1, nwv);
    for (int l = 1; l < 3; ++l) {
        k_gemm1<<<gG1, 256, 0, stream>>>(act, WcT + l * 256 * CH, B1[l], Pb, Qb, N);
        int flags = (l < 2) ? 1 : 2;
        k_node<<<gNode, 256, 0, stream>>>(Pb, Qb, W2T + l * CH * CH, B2[l],
                                          row_ptr, sed, act, (float*)d_out, N, flags, nwv);
    }
}